// Round 9
// baseline (166.075 us; speedup 1.0000x reference)
//
#include <hip/hip_runtime.h>

#define BTOT 8192
#define TT 512

__device__ __forceinline__ float bperm(int addr4, float v) {
    return __int_as_float(__builtin_amdgcn_ds_bpermute(addr4, __float_as_int(v)));
}

// soft reciprocal: magic seed + 2 Newton -> ~1e-6 rel err, all-VALU (depth ~40cy)
__device__ __forceinline__ float srcp(float d) {
    float r = __int_as_float(0x7EF311C3 - __float_as_int(d));
    r = r * fmaf(-d, r, 2.0f);
    r = r * fmaf(-d, r, 2.0f);
    return r;
}

// tanh Pade[7/6]: tanh(t) ~ t*(135135+17325u+378u^2+u^3)/(135135+62370u+3150u^2+28u^3)
// err <= ~2e-5 on [-4,4], ~1e-4 at clamp edge |t|=5. (Proven in R8: absmax at bf16 floor.)
__device__ __forceinline__ void tanh_parts(float t, float& num, float& den) {
    const float u = t * t;
    float np = u + 378.0f;
    np = fmaf(np, u, 17325.0f);
    np = fmaf(np, u, 135135.0f);
    num = t * np;
    float dp = fmaf(28.0f, u, 3150.0f);
    dp = fmaf(dp, u, 62370.0f);
    den = fmaf(dp, u, 135135.0f);
}

__global__ __launch_bounds__(64) void lstm_kernel(
    const float* __restrict__ x,
    const float* __restrict__ W_ih,
    const float* __restrict__ W_hh,
    const float* __restrict__ b_ih,
    const float* __restrict__ b_hh,
    const float* __restrict__ fc1_w,
    const float* __restrict__ fc1_b,
    const float* __restrict__ fc2_w,
    const float* __restrict__ fc2_b,
    float* __restrict__ out)
{
    const int lane = threadIdx.x;               // one wave per block
    const int ll   = (lane < 40) ? lane : 39;   // lanes 40-63 idle, alias group 7
    const int grp  = ll / 5;                    // batch slot within wave: 0..7
    const int j    = ll - grp * 5;              // hidden unit owned: 0..4
    const int gb   = grp * 5;                   // group base lane
    const int b    = blockIdx.x * 8 + grp;      // exact: 1024*8 = 8192
    const bool wr  = (lane < 40) && (j == 0);

    // Lane owns all 4 gate rows (i,f,g,o) of unit j.
    // sigmoid(z) = 0.5 + 0.5*tanh(z/2): fold the 0.5 into i,f,o weights.
    float wih[4][5], whh[4][5], bv[4];
    #pragma unroll
    for (int r = 0; r < 4; ++r) {
        const float s = (r == 2) ? 1.0f : 0.5f;
        const int row = r * 5 + j;              // PyTorch gate-major
        #pragma unroll
        for (int i = 0; i < 5; ++i) {
            wih[r][i] = s * W_ih[row * 5 + i];
            whh[r][i] = s * W_hh[row * 5 + i];
        }
        bv[r] = s * (b_ih[row] + b_hh[row]);
    }

    // h_k lives on lane gb+k
    int a_h[5];
    #pragma unroll
    for (int k = 0; k < 5; ++k) a_h[k] = (gb + k) << 2;

    const float* xb = x + (size_t)b * (TT * 5);

    float hv[5] = {0.f, 0.f, 0.f, 0.f, 0.f};
    float C = 0.f;

    float4 bufA[5], bufB[5];
    #pragma unroll
    for (int i = 0; i < 5; ++i) {
        bufA[i] = *(const float4*)(xb + 0  + 4 * i);   // t = 0..3
        bufB[i] = *(const float4*)(xb + 20 + 4 * i);   // t = 4..7
    }

    auto process4 = [&](const float4* buf) {
        float xs[20];
        *(float4*)&xs[0]  = buf[0];
        *(float4*)&xs[4]  = buf[1];
        *(float4*)&xs[8]  = buf[2];
        *(float4*)&xs[12] = buf[3];
        *(float4*)&xs[16] = buf[4];

        // x-projection for all 4 rows of one step
        auto proj = [&](int s, float* gx) {
            #pragma unroll
            for (int r = 0; r < 4; ++r) {
                float a = bv[r];
                #pragma unroll
                for (int i = 0; i < 5; ++i) a = fmaf(wih[r][i], xs[s * 5 + i], a);
                gx[r] = a;
            }
        };

        float gxc[4];
        proj(0, gxc);

        #pragma unroll
        for (int s = 0; s < 4; ++s) {
            // 4 recurrent dots (independent chains)
            float z[4];
            #pragma unroll
            for (int r = 0; r < 4; ++r) {
                float a = gxc[r];
                #pragma unroll
                for (int k = 0; k < 5; ++k) a = fmaf(whh[r][k], hv[k], a);
                z[r] = a;
            }

            // 4 activations via Pade rational, fully parallel (chain = 1 site)
            float val[4];
            #pragma unroll
            for (int r = 0; r < 4; ++r) {
                const float t = __builtin_amdgcn_fmed3f(z[r], -5.0f, 5.0f);
                float num, den;
                tanh_parts(t, num, den);
                const float rr = srcp(den);
                if (r == 2) {
                    val[r] = num * rr;                               // tanh(z)
                } else {
                    const float pre = fmaf(0.5f, num, 0.5f * den);   // sigmoid(z)
                    val[r] = pre * rr;
                }
            }

            // cell update + output tanh (the only serial part besides bperm)
            C = fmaf(val[1], C, val[0] * val[2]);
            const float t2 = __builtin_amdgcn_fmed3f(C, -5.0f, 5.0f);
            float num2, den2;
            tanh_parts(t2, num2, den2);
            const float h = val[3] * (num2 * srcp(den2));

            // single 5-value bperm round: gather h_0..h_4 of this group
            #pragma unroll
            for (int k = 0; k < 5; ++k) hv[k] = bperm(a_h[k], h);

            // fill the bperm shadow with next step's x-projection
            if (s < 3) proj(s + 1, gxc);
        }
    };

    for (int t0 = 0; t0 < TT; t0 += 8) {
        process4(bufA);                                // steps t0 .. t0+3
        {
            const int tld = (t0 + 8 <= TT - 4) ? (t0 + 8) : (TT - 4);
            const float* p = xb + tld * 5;
            #pragma unroll
            for (int i = 0; i < 5; ++i) bufA[i] = *(const float4*)(p + 4 * i);
        }
        process4(bufB);                                // steps t0+4 .. t0+7
        {
            const int tld = (t0 + 12 <= TT - 4) ? (t0 + 12) : (TT - 4);
            const float* p = xb + tld * 5;
            #pragma unroll
            for (int i = 0; i < 5; ++i) bufB[i] = *(const float4*)(p + 4 * i);
        }
    }

    // hv holds the final hidden state replicated across the group
    if (wr) {
        float p = fc1_b[0];
        float v = fc2_b[0];
        #pragma unroll
        for (int k = 0; k < 5; ++k) {
            p = fmaf(fc1_w[k], hv[k], p);
            v = fmaf(fc2_w[k], hv[k], v);
        }
        out[b] = p;
        out[BTOT + b] = v;
    }
}

extern "C" void kernel_launch(void* const* d_in, const int* in_sizes, int n_in,
                              void* d_out, int out_size, void* d_ws, size_t ws_size,
                              hipStream_t stream) {
    const float* x     = (const float*)d_in[0];
    const float* W_ih  = (const float*)d_in[1];
    const float* W_hh  = (const float*)d_in[2];
    const float* b_ih  = (const float*)d_in[3];
    const float* b_hh  = (const float*)d_in[4];
    const float* fc1_w = (const float*)d_in[5];
    const float* fc1_b = (const float*)d_in[6];
    const float* fc2_w = (const float*)d_in[7];
    const float* fc2_b = (const float*)d_in[8];
    float* out = (float*)d_out;

    const int blocks = BTOT / 8;   // 1024 one-wave blocks, 8 batches each -> K=1, all SIMDs busy
    lstm_kernel<<<blocks, 64, 0, stream>>>(x, W_ih, W_hh, b_ih, b_hh,
                                           fc1_w, fc1_b, fc2_w, fc2_b, out);
}